// Round 1
// baseline (594.894 us; speedup 1.0000x reference)
//
#include <hip/hip_runtime.h>
#include <hip/hip_bf16.h>

// Problem constants (from reference)
#define NH   32
#define HD   128
#define NKV  8
#define GQ   4        // NH / NKV
#define BS   16
#define NB   4096
#define MB   128
#define SEQ  32
#define LKV  2048     // MB * BS
#define SPLITS 4
#define CHUNK  512    // LKV / SPLITS
#define ROWS   8      // tokens in flight per step (256 threads / 32 lanes-per-token)
#define STEPS  8
#define TILE   64     // ROWS * STEPS

__constant__ float SCALE_RSQRT = 0.08838834764831845f; // 1/sqrt(128)

typedef float v2f __attribute__((ext_vector_type(2)));

// Round f32 -> fp8 e4m3fn (OCP on gfx950, RNE) -> f32
__device__ __forceinline__ float fp8_round1(float x) {
  int p = __builtin_amdgcn_cvt_pk_fp8_f32(x, x, 0, false);
  return __builtin_amdgcn_cvt_f32_fp8(p, 0);
}

// RNE round f32 -> bf16 -> f32
__device__ __forceinline__ float bf16r(float x) {
  unsigned u = __float_as_uint(x);
  u = (u + 0x7fffu + ((u >> 16) & 1u)) & 0xffff0000u;
  return __uint_as_float(u);
}

// Dequant 4 cache floats: fp8-round, * scale, bf16-round
__device__ __forceinline__ float4 deq4(float4 x, float sc) {
  int p0 = __builtin_amdgcn_cvt_pk_fp8_f32(x.x, x.y, 0, false);
  int p1 = __builtin_amdgcn_cvt_pk_fp8_f32(x.z, x.w, 0, false);
  v2f a = __builtin_amdgcn_cvt_pk_f32_fp8(p0, false);
  v2f b = __builtin_amdgcn_cvt_pk_f32_fp8(p1, false);
  float4 r;
  r.x = bf16r(a.x * sc);
  r.y = bf16r(a.y * sc);
  r.z = bf16r(b.x * sc);
  r.w = bf16r(b.y * sc);
  return r;
}

// ---------------------------------------------------------------------------
// Kernel 1: quantize new K/V token and scatter into the caches
// ---------------------------------------------------------------------------
__global__ void scatter_kv(const float* __restrict__ k,
                           const float* __restrict__ v,
                           const float* __restrict__ k_scale,
                           const float* __restrict__ v_scale,
                           const int* __restrict__ slot_mapping,
                           float* __restrict__ k_cache,
                           float* __restrict__ v_cache) {
  int idx = blockIdx.x * blockDim.x + threadIdx.x; // [0, SEQ*NKV*HD)
  if (idx >= SEQ * NKV * HD) return;
  int d = idx & (HD - 1);
  int h = (idx >> 7) & (NKV - 1);
  int s = idx >> 10; // / (NKV*HD)
  int slot = slot_mapping[s];
  size_t coff = ((size_t)slot * NKV + h) * HD + d;
  k_cache[coff] = fp8_round1(k[idx] / k_scale[h]);
  v_cache[coff] = fp8_round1(v[idx] / v_scale[h]);
}

// ---------------------------------------------------------------------------
// Kernel 2: split-K flash-decode attention
// grid: SEQ * NKV * SPLITS workgroups of 256 threads
// o_part: [SEQ][NKV][SPLITS][GQ][HD] f32, ml_part: [SEQ][NKV][SPLITS][GQ] float2
// ---------------------------------------------------------------------------
__global__ __launch_bounds__(256, 2)
void attn_split(const float* __restrict__ q,
                const float* __restrict__ k_cache,
                const float* __restrict__ v_cache,
                const float* __restrict__ k_scale,
                const float* __restrict__ v_scale,
                const int* __restrict__ block_tables,
                const int* __restrict__ context_lens,
                float* __restrict__ o_part,
                float2* __restrict__ ml_part) {
  const int wg = blockIdx.x;
  const int split = wg % SPLITS;
  const int h = (wg / SPLITS) % NKV;
  const int s = wg / (SPLITS * NKV);
  const int ctx = context_lens[s];
  const int start = split * CHUNK;
  const int end = min(ctx, start + CHUNK);

  const int tid = threadIdx.x;
  const int lane = tid & 31;   // lane within 32-thread token group
  const int wave = tid >> 6;   // 0..3
  const int grp = tid >> 5;    // 0..7 token row
  const int dbase = lane * 4;

  const float ks = k_scale[h];
  const float vs = v_scale[h];

  __shared__ float red_max[4][GQ];
  __shared__ float red_l[4][GQ];
  __shared__ float red_o[4][32][GQ * 4]; // 8 KB

  // q fragments (pre-scaled by 1/sqrt(HD))
  float4 qv[GQ];
#pragma unroll
  for (int g = 0; g < GQ; ++g) {
    float4 t = *(const float4*)(q + ((size_t)s * NH + h * GQ + g) * HD + dbase);
    qv[g].x = t.x * SCALE_RSQRT;
    qv[g].y = t.y * SCALE_RSQRT;
    qv[g].z = t.z * SCALE_RSQRT;
    qv[g].w = t.w * SCALE_RSQRT;
  }

  float m[GQ], l[GQ];
  float4 oacc[GQ];
#pragma unroll
  for (int g = 0; g < GQ; ++g) {
    m[g] = -1e30f;
    l[g] = 0.0f;
    oacc[g] = make_float4(0.f, 0.f, 0.f, 0.f);
  }

  for (int t0 = start; t0 < end; t0 += TILE) {
    float sc[STEPS][GQ];
    float4 vv[STEPS];
#pragma unroll
    for (int st = 0; st < STEPS; ++st) {
      int t = t0 + st * ROWS + grp;
      float4 kk = make_float4(0.f, 0.f, 0.f, 0.f);
      float4 vt = make_float4(0.f, 0.f, 0.f, 0.f);
      bool valid = (t < end);
      if (valid) {
        int blk = block_tables[s * MB + (t >> 4)];
        size_t off = ((((size_t)blk << 4) + (t & 15)) * NKV + h) * HD + dbase;
        kk = *(const float4*)(k_cache + off);
        vt = *(const float4*)(v_cache + off);
      }
      kk = deq4(kk, ks);
      vv[st] = deq4(vt, vs);
#pragma unroll
      for (int g = 0; g < GQ; ++g) {
        float d = kk.x * qv[g].x + kk.y * qv[g].y + kk.z * qv[g].z + kk.w * qv[g].w;
        d += __shfl_xor(d, 1);
        d += __shfl_xor(d, 2);
        d += __shfl_xor(d, 4);
        d += __shfl_xor(d, 8);
        d += __shfl_xor(d, 16);
        sc[st][g] = valid ? d : -1e30f;
      }
    }

    // tile max per head (wave butterfly then LDS across waves)
    float tmax[GQ];
#pragma unroll
    for (int g = 0; g < GQ; ++g) {
      float v0 = sc[0][g];
#pragma unroll
      for (int st = 1; st < STEPS; ++st) v0 = fmaxf(v0, sc[st][g]);
#pragma unroll
      for (int mk = 32; mk >= 1; mk >>= 1) v0 = fmaxf(v0, __shfl_xor(v0, mk));
      tmax[g] = v0;
    }
    if ((tid & 63) == 0) {
#pragma unroll
      for (int g = 0; g < GQ; ++g) red_max[wave][g] = tmax[g];
    }
    __syncthreads();

    float mnew[GQ], alpha[GQ];
#pragma unroll
    for (int g = 0; g < GQ; ++g) {
      float tm = fmaxf(fmaxf(red_max[0][g], red_max[1][g]),
                       fmaxf(red_max[2][g], red_max[3][g]));
      mnew[g] = fmaxf(m[g], tm);
      alpha[g] = __expf(m[g] - mnew[g]);
    }

    // p = exp(s - mnew); accumulate l
    float lpart[GQ] = {0.f, 0.f, 0.f, 0.f};
#pragma unroll
    for (int st = 0; st < STEPS; ++st) {
#pragma unroll
      for (int g = 0; g < GQ; ++g) {
        float p = __expf(sc[st][g] - mnew[g]);
        sc[st][g] = p;
        lpart[g] += p;
      }
    }
    // lpart is replicated within each 32-lane group; sum the wave's two groups
#pragma unroll
    for (int g = 0; g < GQ; ++g) lpart[g] += __shfl_xor(lpart[g], 32);
    if ((tid & 63) == 0) {
#pragma unroll
      for (int g = 0; g < GQ; ++g) red_l[wave][g] = lpart[g];
    }
    __syncthreads();
#pragma unroll
    for (int g = 0; g < GQ; ++g) {
      float ladd = red_l[0][g] + red_l[1][g] + red_l[2][g] + red_l[3][g];
      l[g] = l[g] * alpha[g] + ladd;
      // o update for this head
      float4 acc = make_float4(0.f, 0.f, 0.f, 0.f);
#pragma unroll
      for (int st = 0; st < STEPS; ++st) {
        acc.x += sc[st][g] * vv[st].x;
        acc.y += sc[st][g] * vv[st].y;
        acc.z += sc[st][g] * vv[st].z;
        acc.w += sc[st][g] * vv[st].w;
      }
      oacc[g].x = oacc[g].x * alpha[g] + acc.x;
      oacc[g].y = oacc[g].y * alpha[g] + acc.y;
      oacc[g].z = oacc[g].z * alpha[g] + acc.z;
      oacc[g].w = oacc[g].w * alpha[g] + acc.w;
      m[g] = mnew[g];
    }
  }

  // combine the wave's two token groups (same d-slice, different tokens)
#pragma unroll
  for (int g = 0; g < GQ; ++g) {
    oacc[g].x += __shfl_xor(oacc[g].x, 32);
    oacc[g].y += __shfl_xor(oacc[g].y, 32);
    oacc[g].z += __shfl_xor(oacc[g].z, 32);
    oacc[g].w += __shfl_xor(oacc[g].w, 32);
  }
  __syncthreads(); // protect red_* reuse ordering
  if (!(tid & 32)) {
#pragma unroll
    for (int g = 0; g < GQ; ++g) {
      red_o[wave][lane][g * 4 + 0] = oacc[g].x;
      red_o[wave][lane][g * 4 + 1] = oacc[g].y;
      red_o[wave][lane][g * 4 + 2] = oacc[g].z;
      red_o[wave][lane][g * 4 + 3] = oacc[g].w;
    }
  }
  __syncthreads();

  if (tid < 128) {
    int g = tid >> 5;
    int ln = tid & 31;
    float4 r;
    r.x = red_o[0][ln][g * 4 + 0] + red_o[1][ln][g * 4 + 0] +
          red_o[2][ln][g * 4 + 0] + red_o[3][ln][g * 4 + 0];
    r.y = red_o[0][ln][g * 4 + 1] + red_o[1][ln][g * 4 + 1] +
          red_o[2][ln][g * 4 + 1] + red_o[3][ln][g * 4 + 1];
    r.z = red_o[0][ln][g * 4 + 2] + red_o[1][ln][g * 4 + 2] +
          red_o[2][ln][g * 4 + 2] + red_o[3][ln][g * 4 + 2];
    r.w = red_o[0][ln][g * 4 + 3] + red_o[1][ln][g * 4 + 3] +
          red_o[2][ln][g * 4 + 3] + red_o[3][ln][g * 4 + 3];
    size_t ob = ((((size_t)s * NKV + h) * SPLITS + split) * GQ + g) * HD + ln * 4;
    *(float4*)(o_part + ob) = r;
  }
  if (tid < GQ) {
    ml_part[(((size_t)s * NKV + h) * SPLITS + split) * GQ + tid] =
        make_float2(m[tid], l[tid]);
  }
}

// ---------------------------------------------------------------------------
// Kernel 3: combine split partials
// grid: SEQ*NKV blocks of 128 threads (thread = d), loop over g
// ---------------------------------------------------------------------------
__global__ void combine_splits(const float* __restrict__ o_part,
                               const float2* __restrict__ ml_part,
                               float* __restrict__ out) {
  int b = blockIdx.x;
  int h = b % NKV;
  int s = b / NKV;
  int d = threadIdx.x;
#pragma unroll
  for (int g = 0; g < GQ; ++g) {
    float2 ml[SPLITS];
    float M = -1e30f;
#pragma unroll
    for (int i = 0; i < SPLITS; ++i) {
      ml[i] = ml_part[(((size_t)s * NKV + h) * SPLITS + i) * GQ + g];
      M = fmaxf(M, ml[i].x);
    }
    float L = 0.f;
    float acc = 0.f;
#pragma unroll
    for (int i = 0; i < SPLITS; ++i) {
      float w = __expf(ml[i].x - M);
      L += ml[i].y * w;
      acc += w * o_part[((((size_t)s * NKV + h) * SPLITS + i) * GQ + g) * HD + d];
    }
    out[((size_t)s * NH + h * GQ + g) * HD + d] = acc / L;
  }
}

// ---------------------------------------------------------------------------
extern "C" void kernel_launch(void* const* d_in, const int* in_sizes, int n_in,
                              void* d_out, int out_size, void* d_ws, size_t ws_size,
                              hipStream_t stream) {
  const float* q        = (const float*)d_in[0];
  const float* k        = (const float*)d_in[1];
  const float* v        = (const float*)d_in[2];
  float*       k_cache  = (float*)d_in[3];
  float*       v_cache  = (float*)d_in[4];
  const float* k_scale  = (const float*)d_in[5];
  const float* v_scale  = (const float*)d_in[6];
  const int*   slot_map = (const int*)d_in[7];
  const int*   btables  = (const int*)d_in[8];
  const int*   ctx_lens = (const int*)d_in[9];
  float*       out      = (float*)d_out;

  // workspace layout: o_part then ml_part
  float*  o_part  = (float*)d_ws;
  float2* ml_part = (float2*)((char*)d_ws + (size_t)SEQ * NKV * SPLITS * GQ * HD * sizeof(float));

  // 1) scatter quantized new K/V into caches
  scatter_kv<<<(SEQ * NKV * HD + 255) / 256, 256, 0, stream>>>(
      k, v, k_scale, v_scale, slot_map, k_cache, v_cache);

  // 2) split-K flash decode
  attn_split<<<SEQ * NKV * SPLITS, 256, 0, stream>>>(
      q, k_cache, v_cache, k_scale, v_scale, btables, ctx_lens, o_part, ml_part);

  // 3) combine
  combine_splits<<<SEQ * NKV, 128, 0, stream>>>(o_part, ml_part, out);
}

// Round 2
// 486.525 us; speedup vs baseline: 1.2227x; 1.2227x over previous
//
#include <hip/hip_runtime.h>
#include <hip/hip_bf16.h>

// Problem constants (from reference)
#define NH   32
#define HD   128
#define NKV  8
#define GQ   4        // NH / NKV
#define BS   16
#define NB   4096
#define MB   128
#define SEQ  32
#define WPG  8        // workgroups per (s,h)
#define UPW  8        // half-wave units per workgroup (256 thr / 32)
#define NSPLIT (WPG*UPW)   // 64 strided splits per (s,h)
#define UNROLL 4

__constant__ float SCALE_RSQRT = 0.08838834764831845f; // 1/sqrt(128)

typedef float v2f __attribute__((ext_vector_type(2)));

// RNE round f32 -> bf16 -> f32
__device__ __forceinline__ float bf16r(float x) {
  unsigned u = __float_as_uint(x);
  u = (u + 0x7fffu + ((u >> 16) & 1u)) & 0xffff0000u;
  return __uint_as_float(u);
}

// Dequant 4 cache floats: fp8(e4m3fn, RNE) round, * scale, bf16 RNE round.
// (Cache values are already fp8-representable, so the fp8 pass is exact for
// them; for the fresh token we pre-divide by scale and this performs the
// actual quantization, matching the reference bit-for-bit.)
__device__ __forceinline__ float4 deq4(float4 x, float sc) {
  int p0 = __builtin_amdgcn_cvt_pk_fp8_f32(x.x, x.y, 0, false);
  int p1 = __builtin_amdgcn_cvt_pk_fp8_f32(x.z, x.w, 0, false);
  v2f a = __builtin_amdgcn_cvt_pk_f32_fp8(p0, false);
  v2f b = __builtin_amdgcn_cvt_pk_f32_fp8(p1, false);
  float4 r;
  r.x = bf16r(a.x * sc);
  r.y = bf16r(a.y * sc);
  r.z = bf16r(b.x * sc);
  r.w = bf16r(b.y * sc);
  return r;
}

// ---------------------------------------------------------------------------
// Split-K flash decode. One 32-lane unit owns tokens {u, u+64, u+128, ...}.
// No __syncthreads in the main loop; softmax state is lane-local.
// o_part: [SEQ][NKV][WPG][GQ][HD] f32 ; ml_part: [SEQ][NKV][WPG][GQ] float2
// ---------------------------------------------------------------------------
__global__ __launch_bounds__(256, 4)
void attn_split(const float* __restrict__ q,
                const float* __restrict__ knew,
                const float* __restrict__ vnew,
                const float* __restrict__ k_cache,
                const float* __restrict__ v_cache,
                const float* __restrict__ k_scale,
                const float* __restrict__ v_scale,
                const int* __restrict__ block_tables,
                const int* __restrict__ context_lens,
                float* __restrict__ o_part,
                float2* __restrict__ ml_part) {
  const int wg = blockIdx.x;
  const int wgsub = wg % WPG;
  const int h = (wg / WPG) % NKV;
  const int s = wg / (WPG * NKV);
  const int tid = threadIdx.x;
  const int lane = tid & 31;
  const int unit = tid >> 5;            // 0..7 within WG
  const int ug = wgsub * UPW + unit;    // 0..63 global split id
  const int dbase = lane * 4;

  __shared__ int bt[MB];                // this seq's block table
  __shared__ float so[UPW][GQ][HD];     // 16 KB epilogue buffer
  __shared__ float2 sml[UPW][GQ];

  if (tid < MB) bt[tid] = block_tables[s * MB + tid];
  __syncthreads();

  const int ctx = context_lens[s];
  const int last = ctx - 1;             // position of the fresh token
  const float ks = k_scale[h];
  const float vs = v_scale[h];

  // q fragment, pre-scaled
  float4 qv[GQ];
#pragma unroll
  for (int g = 0; g < GQ; ++g) {
    float4 t = *(const float4*)(q + ((size_t)s * NH + h * GQ + g) * HD + dbase);
    qv[g].x = t.x * SCALE_RSQRT;
    qv[g].y = t.y * SCALE_RSQRT;
    qv[g].z = t.z * SCALE_RSQRT;
    qv[g].w = t.w * SCALE_RSQRT;
  }

  float m[GQ], l[GQ];
  float4 oacc[GQ];
#pragma unroll
  for (int g = 0; g < GQ; ++g) {
    m[g] = -1e30f;
    l[g] = 0.0f;
    oacc[g] = make_float4(0.f, 0.f, 0.f, 0.f);
  }

  // ---- fresh token (position last): quantize from knew/vnew, bypass cache
  if (ug == (last & (NSPLIT - 1))) {
    float4 kk = *(const float4*)(knew + ((size_t)s * NKV + h) * HD + dbase);
    float4 vt = *(const float4*)(vnew + ((size_t)s * NKV + h) * HD + dbase);
    kk.x /= ks; kk.y /= ks; kk.z /= ks; kk.w /= ks;
    vt.x /= vs; vt.y /= vs; vt.z /= vs; vt.w /= vs;
    kk = deq4(kk, ks);
    vt = deq4(vt, vs);
#pragma unroll
    for (int g = 0; g < GQ; ++g) {
      float d = kk.x * qv[g].x + kk.y * qv[g].y + kk.z * qv[g].z + kk.w * qv[g].w;
      d += __shfl_xor(d, 1);
      d += __shfl_xor(d, 2);
      d += __shfl_xor(d, 4);
      d += __shfl_xor(d, 8);
      d += __shfl_xor(d, 16);
      m[g] = d;
      l[g] = 1.0f;                      // exp(d - d)
      oacc[g] = vt;                     // p * v with p = 1
    }
  }

  // ---- main loop over this unit's strided tokens (skip `last`)
  for (int t0 = ug; t0 < ctx; t0 += NSPLIT * UNROLL) {
    float4 kk[UNROLL], vv[UNROLL];
    bool val[UNROLL];
#pragma unroll
    for (int i = 0; i < UNROLL; ++i) {
      int t = t0 + i * NSPLIT;
      val[i] = (t < ctx) && (t != last);
      kk[i] = make_float4(0.f, 0.f, 0.f, 0.f);
      vv[i] = make_float4(0.f, 0.f, 0.f, 0.f);
      if (val[i]) {
        int blk = bt[t >> 4];
        size_t off = (((size_t)blk * BS + (t & (BS - 1))) * NKV + h) * HD + dbase;
        kk[i] = *(const float4*)(k_cache + off);
        vv[i] = *(const float4*)(v_cache + off);
      }
    }

    float sc[UNROLL][GQ];
#pragma unroll
    for (int i = 0; i < UNROLL; ++i) {
      float4 kd = deq4(kk[i], ks);
      vv[i] = deq4(vv[i], vs);
#pragma unroll
      for (int g = 0; g < GQ; ++g) {
        float d = kd.x * qv[g].x + kd.y * qv[g].y + kd.z * qv[g].z + kd.w * qv[g].w;
        d += __shfl_xor(d, 1);
        d += __shfl_xor(d, 2);
        d += __shfl_xor(d, 4);
        d += __shfl_xor(d, 8);
        d += __shfl_xor(d, 16);
        sc[i][g] = val[i] ? d : -1e30f;
      }
    }

#pragma unroll
    for (int g = 0; g < GQ; ++g) {
      float tm = sc[0][g];
#pragma unroll
      for (int i = 1; i < UNROLL; ++i) tm = fmaxf(tm, sc[i][g]);
      float mnew = fmaxf(m[g], tm);
      float alpha = __expf(m[g] - mnew);
      float p[UNROLL];
      float lad = 0.f;
#pragma unroll
      for (int i = 0; i < UNROLL; ++i) {
        p[i] = __expf(sc[i][g] - mnew);
        lad += p[i];
      }
      l[g] = l[g] * alpha + lad;
      float4 acc = make_float4(0.f, 0.f, 0.f, 0.f);
#pragma unroll
      for (int i = 0; i < UNROLL; ++i) {
        acc.x += p[i] * vv[i].x;
        acc.y += p[i] * vv[i].y;
        acc.z += p[i] * vv[i].z;
        acc.w += p[i] * vv[i].w;
      }
      oacc[g].x = oacc[g].x * alpha + acc.x;
      oacc[g].y = oacc[g].y * alpha + acc.y;
      oacc[g].z = oacc[g].z * alpha + acc.z;
      oacc[g].w = oacc[g].w * alpha + acc.w;
      m[g] = mnew;
    }
  }

  // ---- intra-WG combine of the 8 units
#pragma unroll
  for (int g = 0; g < GQ; ++g)
    *(float4*)&so[unit][g][dbase] = oacc[g];
  if (lane == 0) {
#pragma unroll
    for (int g = 0; g < GQ; ++g) sml[unit][g] = make_float2(m[g], l[g]);
  }
  __syncthreads();

  if (tid < 128) {
    int g = tid >> 5;
    int ln = tid & 31;
    float M = -1e30f;
#pragma unroll
    for (int u = 0; u < UPW; ++u) M = fmaxf(M, sml[u][g].x);
    float L = 0.f;
    float4 acc = make_float4(0.f, 0.f, 0.f, 0.f);
#pragma unroll
    for (int u = 0; u < UPW; ++u) {
      float w = __expf(sml[u][g].x - M);
      L += sml[u][g].y * w;
      float4 t = *(const float4*)&so[u][g][ln * 4];
      acc.x += w * t.x;
      acc.y += w * t.y;
      acc.z += w * t.z;
      acc.w += w * t.w;
    }
    size_t ob = ((((size_t)s * NKV + h) * WPG + wgsub) * GQ + g) * HD + ln * 4;
    *(float4*)(o_part + ob) = acc;
    if (ln == 0)
      ml_part[(((size_t)s * NKV + h) * WPG + wgsub) * GQ + g] = make_float2(M, L);
  }
}

// ---------------------------------------------------------------------------
// Combine the WPG workgroup partials per (s,h)
// ---------------------------------------------------------------------------
__global__ void combine_splits(const float* __restrict__ o_part,
                               const float2* __restrict__ ml_part,
                               float* __restrict__ out) {
  int b = blockIdx.x;      // s*NKV + h
  int h = b % NKV;
  int s = b / NKV;
  int d = threadIdx.x;     // 0..127
#pragma unroll
  for (int g = 0; g < GQ; ++g) {
    float2 ml[WPG];
    float M = -1e30f;
#pragma unroll
    for (int i = 0; i < WPG; ++i) {
      ml[i] = ml_part[(((size_t)s * NKV + h) * WPG + i) * GQ + g];
      M = fmaxf(M, ml[i].x);
    }
    float L = 0.f;
    float acc = 0.f;
#pragma unroll
    for (int i = 0; i < WPG; ++i) {
      float w = __expf(ml[i].x - M);
      L += ml[i].y * w;
      acc += w * o_part[((((size_t)s * NKV + h) * WPG + i) * GQ + g) * HD + d];
    }
    out[((size_t)s * NH + h * GQ + g) * HD + d] = acc / L;
  }
}

// ---------------------------------------------------------------------------
extern "C" void kernel_launch(void* const* d_in, const int* in_sizes, int n_in,
                              void* d_out, int out_size, void* d_ws, size_t ws_size,
                              hipStream_t stream) {
  const float* q        = (const float*)d_in[0];
  const float* k        = (const float*)d_in[1];
  const float* v        = (const float*)d_in[2];
  const float* k_cache  = (const float*)d_in[3];
  const float* v_cache  = (const float*)d_in[4];
  const float* k_scale  = (const float*)d_in[5];
  const float* v_scale  = (const float*)d_in[6];
  const int*   btables  = (const int*)d_in[8];
  const int*   ctx_lens = (const int*)d_in[9];
  float*       out      = (float*)d_out;

  // workspace: o_part (4.19 MB) then ml_part (64 KB)
  float*  o_part  = (float*)d_ws;
  float2* ml_part = (float2*)((char*)d_ws +
                     (size_t)SEQ * NKV * WPG * GQ * HD * sizeof(float));

  attn_split<<<SEQ * NKV * WPG, 256, 0, stream>>>(
      q, k, v, k_cache, v_cache, k_scale, v_scale, btables, ctx_lens,
      o_part, ml_part);

  combine_splits<<<SEQ * NKV, 128, 0, stream>>>(o_part, ml_part, out);
}